// Round 2
// baseline (2116.668 us; speedup 1.0000x reference)
//
#include <hip/hip_runtime.h>

typedef __bf16 bf16x8 __attribute__((ext_vector_type(8)));
typedef float  f32x4  __attribute__((ext_vector_type(4)));

#define ATTN_EPS 1e-8f
#define K_SCALE  0.07216878364870322f   // 192^-0.5

struct __align__(16) Smem {
  float slots[8 * 192];
  __bf16 slots_bf[16 * 192];
  __bf16 ln_bf[16 * 192];
  __bf16 q_bf[16 * 192];
  __bf16 upd_bf[16 * 192];
  __bf16 attnT[16 * 256];
  __bf16 a_bf[16 * 768];
  float gx[8 * 577];
  float gh[8 * 577];
  float colsum[8];
  float Lsg[192], Lsb[192], Lfg[192], Lfb[192];
  float Bih[576], Bhh[576], B1s[768], B2s[192], Pb1s[192], Pb2s[192];
};

// swizzled bf16 store: byte = row*strideB + ((col*2) ^ ((row&7)<<4))
__device__ __forceinline__ void st_swz(__bf16* buf, int strideB, int row, int col, float v) {
  *(__bf16*)((char*)buf + row * strideB + ((col * 2) ^ ((row & 7) << 4))) = (__bf16)v;
}

__device__ __forceinline__ f32x4 zero4() { f32x4 z = {0.f, 0.f, 0.f, 0.f}; return z; }

__device__ __forceinline__ float sigm(float x) {
  return __builtin_amdgcn_rcpf(1.f + __expf(-x));
}
__device__ __forceinline__ float tanhfast(float x) {
  float a = fminf(12.f, fmaxf(-12.f, x));
  float e = __expf(2.f * a);
  return (e - 1.f) * __builtin_amdgcn_rcpf(e + 1.f);
}

// A from swizzled LDS (16 rows, stride astrideB), B from global [col][k] k-contig
template <int K>
__device__ __forceinline__ f32x4 mmcore(f32x4 acc, const __bf16* a_lds, int astrideB,
                                        const __bf16* __restrict__ Bg, int ldb,
                                        int col0, int kofs, int lane) {
  int arow = lane & 15, kgr = lane >> 4;
  const char* ab = (const char*)a_lds + arow * astrideB;
  int aswz = (arow & 7) << 4;
  const __bf16* bp = Bg + (col0 + arow) * ldb + kofs + kgr * 8;
#pragma unroll
  for (int ki = 0; ki < K; ++ki) {
    bf16x8 a = *(const bf16x8*)(ab + ((kofs * 2 + ki * 64 + kgr * 16) ^ aswz));
    bf16x8 b = *(const bf16x8*)(bp + ki * 32);
    acc = __builtin_amdgcn_mfma_f32_16x16x32_bf16(a, b, acc, 0, 0, 0);
  }
  return acc;
}

__device__ __forceinline__ void ln_row(Smem& sm, int s, int lane,
                                       const float* g, const float* bta, __bf16* dst) {
  float v0 = sm.slots[s * 192 + lane], v1 = sm.slots[s * 192 + 64 + lane], v2 = sm.slots[s * 192 + 128 + lane];
  float sum = v0 + v1 + v2, sq = v0 * v0 + v1 * v1 + v2 * v2;
#pragma unroll
  for (int m = 1; m < 64; m <<= 1) { sum += __shfl_xor(sum, m, 64); sq += __shfl_xor(sq, m, 64); }
  float mu = sum * (1.f / 192.f);
  float var = sq * (1.f / 192.f) - mu * mu;
  float rs = rsqrtf(var + 1e-5f);
  st_swz(dst, 384, s, lane,       (v0 - mu) * rs * g[lane]       + bta[lane]);
  st_swz(dst, 384, s, lane + 64,  (v1 - mu) * rs * g[lane + 64]  + bta[lane + 64]);
  st_swz(dst, 384, s, lane + 128, (v2 - mu) * rs * g[lane + 128] + bta[lane + 128]);
}

__device__ __forceinline__ void job_gh(Smem& sm, const __bf16* __restrict__ W, int j, int lane) {
  f32x4 acc = mmcore<6>(zero4(), sm.slots_bf, 384, W, 192, j * 16, 0, lane);
  int kgr = lane >> 4, arow = lane & 15;
  if (kgr < 2) {
    int col = j * 16 + arow;
#pragma unroll
    for (int rr = 0; rr < 4; rr++) sm.gh[(kgr * 4 + rr) * 577 + col] = acc[rr];
  }
}

__device__ __forceinline__ void job_gx(Smem& sm, const __bf16* __restrict__ W, int j, int lane) {
  f32x4 acc = mmcore<6>(zero4(), sm.upd_bf, 384, W, 192, j * 16, 0, lane);
  int kgr = lane >> 4, arow = lane & 15;
  if (kgr < 2) {
    int col = j * 16 + arow;
#pragma unroll
    for (int rr = 0; rr < 4; rr++) {
      float sc = __builtin_amdgcn_rcpf(sm.colsum[kgr * 4 + rr]);
      sm.gx[(kgr * 4 + rr) * 577 + col] = acc[rr] * sc;
    }
  }
}

__device__ __forceinline__ void job_q(Smem& sm, const __bf16* __restrict__ W, int j, int lane) {
  f32x4 acc = mmcore<6>(zero4(), sm.ln_bf, 384, W, 192, j * 16, 0, lane);
  int kgr = lane >> 4, arow = lane & 15;
  if (kgr < 2) {
    int col = j * 16 + arow;
#pragma unroll
    for (int rr = 0; rr < 4; rr++) st_swz(sm.q_bf, 384, kgr * 4 + rr, col, acc[rr]);
  }
}

__device__ __forceinline__ void job_upd(Smem& sm, const __bf16* __restrict__ vb, int j, int lane) {
  f32x4 acc = mmcore<8>(zero4(), sm.attnT, 512, vb, 256, j * 16, 0, lane);
  int kgr = lane >> 4, arow = lane & 15;
  if (kgr < 2) {
    int col = j * 16 + arow;
#pragma unroll
    for (int rr = 0; rr < 4; rr++) st_swz(sm.upd_bf, 384, kgr * 4 + rr, col, acc[rr]);
  }
}

__device__ __forceinline__ void job_colsum(Smem& sm, const __bf16* __restrict__ onesM, int lane) {
  f32x4 acc = mmcore<8>(zero4(), sm.attnT, 512, onesM, 256, 0, 0, lane);
  int kgr = lane >> 4, arow = lane & 15;
  if (kgr < 2 && arow == 0) {
#pragma unroll
    for (int rr = 0; rr < 4; rr++) sm.colsum[kgr * 4 + rr] = acc[rr];
  }
}

__device__ __forceinline__ void job_mlp1(Smem& sm, const __bf16* __restrict__ W, int j, int lane) {
  f32x4 acc = mmcore<6>(zero4(), sm.ln_bf, 384, W, 192, j * 16, 0, lane);
  int kgr = lane >> 4, arow = lane & 15;
  if (kgr < 2) {
    int col = j * 16 + arow;
#pragma unroll
    for (int rr = 0; rr < 4; rr++)
      st_swz(sm.a_bf, 1536, kgr * 4 + rr, col, fmaxf(acc[rr] + sm.B1s[col], 0.f));
  }
}

__device__ __forceinline__ void job_mlp2(Smem& sm, const __bf16* __restrict__ W, int j, int lane) {
  f32x4 acc = zero4();
#pragma unroll
  for (int c = 0; c < 4; c++)
    acc = mmcore<6>(acc, sm.a_bf, 1536, W, 768, j * 16, c * 192, lane);
  int kgr = lane >> 4, arow = lane & 15;
  if (kgr < 2) {
    int col = j * 16 + arow;
#pragma unroll
    for (int rr = 0; rr < 4; rr++) {
      int s = kgr * 4 + rr;
      float nv = sm.slots[s * 192 + col] + acc[rr] + sm.B2s[col];
      sm.slots[s * 192 + col] = nv;
      st_swz(sm.slots_bf, 384, s, col, nv);
    }
  }
}

__device__ __forceinline__ void job_pr1(Smem& sm, const __bf16* __restrict__ W, int j, int lane) {
  f32x4 acc = mmcore<6>(zero4(), sm.slots_bf, 384, W, 192, j * 16, 0, lane);
  int kgr = lane >> 4, arow = lane & 15;
  if (kgr < 2) {
    int col = j * 16 + arow;
#pragma unroll
    for (int rr = 0; rr < 4; rr++)
      st_swz(sm.ln_bf, 384, kgr * 4 + rr, col, fmaxf(acc[rr] + sm.Pb1s[col], 0.f));
  }
}

__device__ __forceinline__ void job_pr2(Smem& sm, const __bf16* __restrict__ W, int j, int lane) {
  f32x4 acc = mmcore<6>(zero4(), sm.ln_bf, 384, W, 192, j * 16, 0, lane);
  int kgr = lane >> 4, arow = lane & 15;
  if (kgr < 2) {
    int col = j * 16 + arow;
#pragma unroll
    for (int rr = 0; rr < 4; rr++) {
      int s = kgr * 4 + rr;
      float nv = acc[rr] + sm.Pb2s[col];
      sm.slots[s * 192 + col] = nv;
      st_swz(sm.slots_bf, 384, s, col, nv);
    }
  }
}

__device__ __forceinline__ void gates(Smem& sm, int s, int lane, bool lnff) {
  float nh[3];
#pragma unroll
  for (int j = 0; j < 3; j++) {
    int d = lane + j * 64;
    float xr = sm.gx[s * 577 + d]       + sm.Bih[d];
    float xz = sm.gx[s * 577 + 192 + d] + sm.Bih[192 + d];
    float xn = sm.gx[s * 577 + 384 + d] + sm.Bih[384 + d];
    float hr = sm.gh[s * 577 + d]       + sm.Bhh[d];
    float hz = sm.gh[s * 577 + 192 + d] + sm.Bhh[192 + d];
    float hn = sm.gh[s * 577 + 384 + d] + sm.Bhh[384 + d];
    float rg = sigm(xr + hr);
    float zg = sigm(xz + hz);
    float ng = tanhfast(xn + rg * hn);
    float hv = sm.slots[s * 192 + d];
    float v = (1.f - zg) * ng + zg * hv;
    nh[j] = v;
    sm.slots[s * 192 + d] = v;
    st_swz(sm.slots_bf, 384, s, d, v);
  }
  if (lnff) {
    float sum = nh[0] + nh[1] + nh[2], sq = nh[0] * nh[0] + nh[1] * nh[1] + nh[2] * nh[2];
#pragma unroll
    for (int m = 1; m < 64; m <<= 1) { sum += __shfl_xor(sum, m, 64); sq += __shfl_xor(sq, m, 64); }
    float mu = sum * (1.f / 192.f);
    float var = sq * (1.f / 192.f) - mu * mu;
    float rs = rsqrtf(var + 1e-5f);
#pragma unroll
    for (int j = 0; j < 3; j++) {
      int d = lane + j * 64;
      st_swz(sm.ln_bf, 384, s, d, (nh[j] - mu) * rs * sm.Lfg[d] + sm.Lfb[d]);
    }
  }
}

// ---------------- prep: cast/transpose weights to bf16 (+ ones matrix) ----------------
__global__ __launch_bounds__(256) void prep_kernel(
    const float* __restrict__ Wk, const float* __restrict__ Wv, const float* __restrict__ Wq,
    const float* __restrict__ wih, const float* __restrict__ whh,
    const float* __restrict__ w1, const float* __restrict__ w2,
    const float* __restrict__ p1, const float* __restrict__ p2,
    __bf16* __restrict__ WkvP, __bf16* __restrict__ WqP,
    __bf16* __restrict__ wihB, __bf16* __restrict__ whhB,
    __bf16* __restrict__ w1P, __bf16* __restrict__ w2P,
    __bf16* __restrict__ pr1P, __bf16* __restrict__ pr2P,
    __bf16* __restrict__ onesM) {
  int i = blockIdx.x * 256 + threadIdx.x;
  if (i < 73728) {  // WkvP [384][192], SCALE folded into k half
    int col = i / 192, c = i - col * 192;
    float v = (col < 192) ? Wk[c * 192 + col] * K_SCALE : Wv[c * 192 + (col - 192)];
    WkvP[i] = (__bf16)v; return;
  }
  i -= 73728;
  if (i < 36864) { int col = i / 192, c = i - col * 192; WqP[i] = (__bf16)Wq[c * 192 + col]; return; }
  i -= 36864;
  if (i < 110592) { wihB[i] = (__bf16)wih[i]; return; }
  i -= 110592;
  if (i < 110592) { whhB[i] = (__bf16)whh[i]; return; }
  i -= 110592;
  if (i < 147456) { int o = i / 192, c = i - o * 192; w1P[i] = (__bf16)w1[c * 768 + o]; return; }
  i -= 147456;
  if (i < 147456) { int o = i / 768, c = i - o * 768; w2P[i] = (__bf16)w2[c * 192 + o]; return; }
  i -= 147456;
  if (i < 36864) { int o = i / 192, c = i - o * 192; pr1P[i] = (__bf16)p1[c * 192 + o]; return; }
  i -= 36864;
  if (i < 36864) { int o = i / 192, c = i - o * 192; pr2P[i] = (__bf16)p2[c * 192 + o]; return; }
  i -= 36864;
  if (i < 4096) onesM[i] = (__bf16)1.f;
}

// ---------------- phase 1: LN(inputs) @ [Wk*SCALE | Wv] -> k (row-major), v (transposed) ----------------
__global__ __launch_bounds__(256) void p1_kernel(
    const float* __restrict__ x_in, const float* __restrict__ lng, const float* __restrict__ lnb,
    const __bf16* __restrict__ Wkv, __bf16* __restrict__ k_all, __bf16* __restrict__ v_all) {
  __shared__ __attribute__((aligned(16))) char pool[64 * 200 * 4];
  __shared__ __attribute__((aligned(16))) __bf16 xh[64 * 192];
  __shared__ float gsh[192], bsh[192];
  float* xs = (float*)pool;
  __bf16* kst = (__bf16*)pool;            // [64][192]
  __bf16* vst = (__bf16*)(pool + 24576);  // [192][64]

  const int tid = threadIdx.x;
  const int blk = blockIdx.x;
  const long Rbase = (long)blk * 64;
  if (tid < 192) { gsh[tid] = lng[tid]; bsh[tid] = lnb[tid]; }

  const float* gxp = x_in + Rbase * 192;
  for (int i = tid; i < 64 * 48; i += 256) {
    int row = i / 48, c4 = i - row * 48;
    float4 v = *(const float4*)(gxp + row * 192 + c4 * 4);
    float* d = xs + row * 200 + c4 * 4;
    d[0] = v.x; d[1] = v.y; d[2] = v.z; d[3] = v.w;
  }
  __syncthreads();

  const int r = tid >> 2, coff = (tid & 3) * 48;
  float xr[48];
  const float* src = xs + r * 200 + coff;
#pragma unroll
  for (int j = 0; j < 48; j++) xr[j] = src[j];
  float s = 0.f, sq = 0.f;
#pragma unroll
  for (int j = 0; j < 48; j++) { s += xr[j]; sq += xr[j] * xr[j]; }
  s += __shfl_xor(s, 1, 64);  s += __shfl_xor(s, 2, 64);
  sq += __shfl_xor(sq, 1, 64); sq += __shfl_xor(sq, 2, 64);
  float mu = s * (1.f / 192.f);
  float var = sq * (1.f / 192.f) - mu * mu;
  float rs = rsqrtf(var + 1e-5f);
  {
    char* xrow = (char*)xh + r * 384;
    int swz = (r & 7) << 4;
#pragma unroll
    for (int j = 0; j < 6; j++) {
      bf16x8 o;
#pragma unroll
      for (int e = 0; e < 8; e++) {
        int c = coff + j * 8 + e;
        o[e] = (__bf16)((xr[j * 8 + e] - mu) * rs * gsh[c] + bsh[c]);
      }
      *(bf16x8*)(xrow + (((coff + j * 8) * 2) ^ swz)) = o;
    }
  }
  __syncthreads();

  const int w = tid >> 6, lane = tid & 63;
  const int arow = lane & 15, kgr = lane >> 4;
  const int m0 = w * 16;
  const char* ab = (const char*)xh + (m0 + arow) * 384;
  const int aswz = (arow & 7) << 4;

  for (int nt = 0; nt < 12; nt++) {                  // k columns
    int col = nt * 16 + arow;
    const __bf16* bp = Wkv + col * 192 + kgr * 8;
    f32x4 acc = {0.f, 0.f, 0.f, 0.f};
#pragma unroll
    for (int ki = 0; ki < 6; ki++) {
      bf16x8 a = *(const bf16x8*)(ab + ((ki * 64 + kgr * 16) ^ aswz));
      bf16x8 b = *(const bf16x8*)(bp + ki * 32);
      acc = __builtin_amdgcn_mfma_f32_16x16x32_bf16(a, b, acc, 0, 0, 0);
    }
#pragma unroll
    for (int rr = 0; rr < 4; rr++) kst[(m0 + kgr * 4 + rr) * 192 + col] = (__bf16)acc[rr];
  }
  for (int nt = 0; nt < 12; nt++) {                  // v columns, transposed staging
    int dcol = nt * 16 + arow;
    const __bf16* bp = Wkv + (192 + dcol) * 192 + kgr * 8;
    f32x4 acc = {0.f, 0.f, 0.f, 0.f};
#pragma unroll
    for (int ki = 0; ki < 6; ki++) {
      bf16x8 a = *(const bf16x8*)(ab + ((ki * 64 + kgr * 16) ^ aswz));
      bf16x8 b = *(const bf16x8*)(bp + ki * 32);
      acc = __builtin_amdgcn_mfma_f32_16x16x32_bf16(a, b, acc, 0, 0, 0);
    }
    __bf16 o0 = (__bf16)acc[0], o1 = (__bf16)acc[1], o2 = (__bf16)acc[2], o3 = (__bf16)acc[3];
    __bf16* vp = &vst[dcol * 64 + m0 + kgr * 4];
    vp[0] = o0; vp[1] = o1; vp[2] = o2; vp[3] = o3;
  }
  __syncthreads();

  {
    const uint4* s4 = (const uint4*)kst;
    uint4* d4 = (uint4*)(k_all + Rbase * 192);
    for (int i = tid; i < 1536; i += 256) d4[i] = s4[i];
  }
  {
    int bt = blk >> 2;
    int n0g = (blk & 3) * 64;
    __bf16* vout = v_all + (long)bt * 49152 + n0g;
    for (int i = tid; i < 1536; i += 256) {
      int d = i >> 3, cc = i & 7;
      *(uint4*)((char*)(vout + d * 256) + cc * 16) =
          *(const uint4*)((const char*)vst + d * 128 + cc * 16);
    }
  }
}

// ---------------- phase 2: persistent block per batch, full scan ----------------
__global__ __launch_bounds__(1024) void p2_kernel(
    const __bf16* __restrict__ k_all, const __bf16* __restrict__ v_all,
    const __bf16* __restrict__ WqP, const __bf16* __restrict__ wihB, const __bf16* __restrict__ whhB,
    const __bf16* __restrict__ w1P, const __bf16* __restrict__ w2P,
    const __bf16* __restrict__ pr1P, const __bf16* __restrict__ pr2P,
    const __bf16* __restrict__ onesM,
    const float* __restrict__ noise, const float* __restrict__ mu_p, const float* __restrict__ lsig,
    const float* __restrict__ lnsg, const float* __restrict__ lnsb,
    const float* __restrict__ lnfg, const float* __restrict__ lnfb,
    const float* __restrict__ bih, const float* __restrict__ bhh,
    const float* __restrict__ b1p, const float* __restrict__ b2p,
    const float* __restrict__ prb1, const float* __restrict__ prb2,
    float* __restrict__ out) {
  __shared__ Smem sm;
  const int tid = threadIdx.x;
  const int w = tid >> 6, lane = tid & 63;
  const int b = blockIdx.x;
  const int kgr = lane >> 4, arow = lane & 15;

  for (int i = tid; i < 192; i += 1024) {
    sm.Lsg[i] = lnsg[i]; sm.Lsb[i] = lnsb[i]; sm.Lfg[i] = lnfg[i]; sm.Lfb[i] = lnfb[i];
    sm.B2s[i] = b2p[i]; sm.Pb1s[i] = prb1[i]; sm.Pb2s[i] = prb2[i];
  }
  for (int i = tid; i < 576; i += 1024) { sm.Bih[i] = bih[i]; sm.Bhh[i] = bhh[i]; }
  for (int i = tid; i < 768; i += 1024) sm.B1s[i] = b1p[i];
  for (int i = tid; i < 16 * 192; i += 1024) {
    sm.slots_bf[i] = (__bf16)0.f; sm.ln_bf[i] = (__bf16)0.f;
    sm.q_bf[i] = (__bf16)0.f; sm.upd_bf[i] = (__bf16)0.f;
  }
  for (int i = tid; i < 16 * 256; i += 1024) sm.attnT[i] = (__bf16)0.f;
  for (int i = tid; i < 16 * 768; i += 1024) sm.a_bf[i] = (__bf16)0.f;
  __syncthreads();
  for (int i = tid; i < 1536; i += 1024) {
    int s = i / 192, d = i - s * 192;
    float v = mu_p[d] + __expf(lsig[d]) * noise[(b * 8 + s) * 192 + d];
    sm.slots[i] = v;
    st_swz(sm.slots_bf, 384, s, d, v);
  }
  __syncthreads();

  float* out_slots = out;
  float* out_dots = out + 786432;

  for (int t = 0; t < 16; ++t) {
    const __bf16* kb = k_all + (long)(b * 16 + t) * 49152;  // [256][192]
    const __bf16* vb = v_all + (long)(b * 16 + t) * 49152;  // [192][256]
    for (int it = 0; it < 3; ++it) {
      // P1: LN(slots) on w0-7 || gh jobs 0..15 on w8-15
      if (w < 8) ln_row(sm, w, lane, sm.Lsg, sm.Lsb, sm.ln_bf);
      else { job_gh(sm, whhB, (w - 8), lane); job_gh(sm, whhB, (w - 8) + 8, lane); }
      __syncthreads();
      // P2: q on w0-11 (+gh 16..27) || gh 28..35 on w12-15
      if (w < 12) { job_q(sm, WqP, w, lane); job_gh(sm, whhB, 16 + w, lane); }
      else { job_gh(sm, whhB, 28 + (w - 12), lane); job_gh(sm, whhB, 32 + (w - 12), lane); }
      __syncthreads();
      // P3: dots + softmax + attnT store (all 16 waves)
      {
        f32x4 acc = mmcore<6>(zero4(), sm.q_bf, 384, kb, 192, w * 16, 0, lane);
        float m4 = fmaxf(fmaxf(acc[0], acc[1]), fmaxf(acc[2], acc[3]));
        float m8 = fmaxf(m4, __shfl_xor(m4, 16, 64));
        float p0 = __expf(acc[0] - m8), p1 = __expf(acc[1] - m8);
        float p2v = __expf(acc[2] - m8), p3 = __expf(acc[3] - m8);
        float s4 = p0 + p1 + p2v + p3;
        float den = s4 + __shfl_xor(s4, 16, 64);
        float rden = 1.f / den;
        if (kgr < 2) {
          int n = w * 16 + arow;
          float a0 = p0 * rden, a1 = p1 * rden, a2 = p2v * rden, a3 = p3 * rden;
          if (it == 2)
            *(float4*)(out_dots + ((long)(b * 16 + t) * 256 + n) * 8 + kgr * 4) = make_float4(a0, a1, a2, a3);
          int r0 = kgr * 4;
          st_swz(sm.attnT, 512, r0 + 0, n, a0 + ATTN_EPS);
          st_swz(sm.attnT, 512, r0 + 1, n, a1 + ATTN_EPS);
          st_swz(sm.attnT, 512, r0 + 2, n, a2 + ATTN_EPS);
          st_swz(sm.attnT, 512, r0 + 3, n, a3 + ATTN_EPS);
        }
      }
      __syncthreads();
      // P4: updates (raw) on w0-11 || colsum MFMA on w12
      if (w < 12) job_upd(sm, vb, w, lane);
      else if (w == 12) job_colsum(sm, onesM, lane);
      __syncthreads();
      // P5: gx (scaled by 1/colsum) — 36 jobs
      job_gx(sm, wihB, w, lane);
      job_gx(sm, wihB, w + 16, lane);
      if (w < 4) job_gx(sm, wihB, w + 32, lane);
      __syncthreads();
      // P6: GRU gates + fused FF-LayerNorm (per-slot wave)
      if (w < 8) gates(sm, w, lane, it < 2);
      __syncthreads();
      if (it < 2) {
        // P7: MLP1 — 48 jobs
        job_mlp1(sm, w1P, w, lane);
        job_mlp1(sm, w1P, w + 16, lane);
        job_mlp1(sm, w1P, w + 32, lane);
        __syncthreads();
        // P8: MLP2 + residual
        if (w < 12) job_mlp2(sm, w2P, w, lane);
        __syncthreads();
      }
    }  // it
    // PA: prior MLP layer 1 on w0-11 || out_slots store on w12-15
    if (w < 12) job_pr1(sm, pr1P, w, lane);
    else {
      for (int i = (w - 12) * 64 + lane; i < 384; i += 256)
        *(float4*)(out_slots + (long)(b * 16 + t) * 1536 + i * 4) = *(const float4*)(&sm.slots[i * 4]);
    }
    __syncthreads();
    // PB: prior MLP layer 2 -> carried slots
    if (w < 12) job_pr2(sm, pr2P, w, lane);
    __syncthreads();
  }  // t
}

extern "C" void kernel_launch(void* const* d_in, const int* in_sizes, int n_in,
                              void* d_out, int out_size, void* d_ws, size_t ws_size,
                              hipStream_t stream) {
  const float* inputs = (const float*)d_in[0];
  const float* noise  = (const float*)d_in[1];
  const float* mu     = (const float*)d_in[2];
  const float* lsig   = (const float*)d_in[3];
  const float* ln_in_g = (const float*)d_in[4];
  const float* ln_in_b = (const float*)d_in[5];
  const float* Wk = (const float*)d_in[6];
  const float* Wv = (const float*)d_in[7];
  const float* Wq = (const float*)d_in[8];
  const float* lnsg = (const float*)d_in[9];
  const float* lnsb = (const float*)d_in[10];
  const float* wih = (const float*)d_in[11];
  const float* whh = (const float*)d_in[12];
  const float* bih = (const float*)d_in[13];
  const float* bhh = (const float*)d_in[14];
  const float* lnfg = (const float*)d_in[15];
  const float* lnfb = (const float*)d_in[16];
  const float* w1 = (const float*)d_in[17];
  const float* b1 = (const float*)d_in[18];
  const float* w2 = (const float*)d_in[19];
  const float* b2 = (const float*)d_in[20];
  const float* pw1 = (const float*)d_in[21];
  const float* pb1 = (const float*)d_in[22];
  const float* pw2 = (const float*)d_in[23];
  const float* pb2 = (const float*)d_in[24];

  char* ws = (char*)d_ws;
  __bf16* WkvP = (__bf16*)(ws + 0);
  __bf16* WqP  = (__bf16*)(ws + 147456);
  __bf16* wihB = (__bf16*)(ws + 221184);
  __bf16* whhB = (__bf16*)(ws + 442368);
  __bf16* w1P  = (__bf16*)(ws + 663552);
  __bf16* w2P  = (__bf16*)(ws + 958464);
  __bf16* pr1P = (__bf16*)(ws + 1253376);
  __bf16* pr2P = (__bf16*)(ws + 1327104);
  __bf16* k_all = (__bf16*)(ws + 1400832);
  __bf16* v_all = (__bf16*)(ws + 51732480);
  __bf16* onesM = (__bf16*)(ws + 102064128);
  // total ws usage: 102072320 bytes

  prep_kernel<<<2752, 256, 0, stream>>>(Wk, Wv, Wq, wih, whh, w1, w2, pw1, pw2,
                                        WkvP, WqP, wihB, whhB, w1P, w2P, pr1P, pr2P, onesM);
  p1_kernel<<<2048, 256, 0, stream>>>(inputs, ln_in_g, ln_in_b, WkvP, k_all, v_all);
  p2_kernel<<<32, 1024, 0, stream>>>(k_all, v_all, WqP, wihB, whhB, w1P, w2P, pr1P, pr2P, onesM,
                                     noise, mu, lsig, lnsg, lnsb, lnfg, lnfb,
                                     bih, bhh, b1, b2, pb1, pb2, (float*)d_out);
}

// Round 9
// 2085.869 us; speedup vs baseline: 1.0148x; 1.0148x over previous
//
#include <hip/hip_runtime.h>

typedef __bf16 bf16x8 __attribute__((ext_vector_type(8)));
typedef float  f32x4  __attribute__((ext_vector_type(4)));

#define ATTN_EPS 1e-8f
#define K_SCALE  0.07216878364870322f   // 192^-0.5

struct __align__(16) Smem {
  float slots[8 * 192];
  __bf16 slots_bf[16 * 192];   // swizzled, rows 8-15 zero
  __bf16 ln_bf[16 * 192];      // swizzled, rows 8-15 zero
  __bf16 q_bf[16 * 192];       // swizzled, rows 8-15 zero
  __bf16 upd_bf[16 * 192];     // swizzled, rows 8-15 zero
  __bf16 attnT[16 * 256];      // swizzled, rows 8-15 zero
  __bf16 a_bf[16 * 768];       // swizzled, rows 8-15 zero
  float gx[8 * 577];
  float gh[8 * 577];
  float part_cs[16 * 8];
  float Lsg[192], Lsb[192], Lfg[192], Lfb[192];
  float Bih[576], Bhh[576], B1s[768], B2s[192], Pb1s[192], Pb2s[192];
};

// swizzled bf16 store: byte = row*strideB + ((col*2) ^ ((row&7)<<4))
__device__ __forceinline__ void st_swz(__bf16* buf, int strideB, int row, int col, float v) {
  *(__bf16*)((char*)buf + row * strideB + ((col * 2) ^ ((row & 7) << 4))) = (__bf16)v;
}

__device__ __forceinline__ f32x4 zero4() { f32x4 z = {0.f, 0.f, 0.f, 0.f}; return z; }

// A: swizzled LDS tile (16 rows at abase, stride astrideB). bp: per-lane B ptr
// = B + (col0+arow)*ldb + kgr*8 (k-contiguous). Returns D[row=kgr*4+rr][col0+arow].
template <int K>
__device__ __forceinline__ f32x4 mmK(f32x4 acc, const char* abase, int astrideB,
                                     const __bf16* __restrict__ bp, int lane) {
  int arow = lane & 15;
  const char* ab = abase + arow * astrideB;
  int aswz = (arow & 7) << 4;
  int kb0 = (lane >> 4) * 16;
#pragma unroll
  for (int ki = 0; ki < K; ++ki) {
    bf16x8 a = *(const bf16x8*)(ab + ((kb0 + ki * 64) ^ aswz));
    bf16x8 b = *(const bf16x8*)(bp + ki * 32);
    acc = __builtin_amdgcn_mfma_f32_16x16x32_bf16(a, b, acc, 0, 0, 0);
  }
  return acc;
}

__device__ __forceinline__ void st_f32(float* dst577, f32x4 acc, int col0, int lane) {
  int kgr = lane >> 4, arow = lane & 15;
  if (kgr < 2) {
    int c = col0 + arow;
#pragma unroll
    for (int rr = 0; rr < 4; rr++) dst577[(kgr * 4 + rr) * 577 + c] = acc[rr];
  }
}

__device__ __forceinline__ void st_q_swz(__bf16* dst, f32x4 acc, int col0, int lane) {
  int kgr = lane >> 4, arow = lane & 15;
  if (kgr < 2) {
    int c = col0 + arow;
#pragma unroll
    for (int rr = 0; rr < 4; rr++) st_swz(dst, 384, kgr * 4 + rr, c, acc[rr]);
  }
}

__device__ __forceinline__ void st_relu_swz(__bf16* dst, int strideB, f32x4 acc,
                                            int col0, const float* bias, int lane) {
  int kgr = lane >> 4, arow = lane & 15;
  if (kgr < 2) {
    int c = col0 + arow;
#pragma unroll
    for (int rr = 0; rr < 4; rr++)
      st_swz(dst, strideB, kgr * 4 + rr, c, fmaxf(acc[rr] + bias[c], 0.f));
  }
}

// ---------------- prep: cast/transpose weights to bf16 ----------------
__global__ __launch_bounds__(256) void prep_kernel(
    const float* __restrict__ Wk, const float* __restrict__ Wv, const float* __restrict__ Wq,
    const float* __restrict__ wih, const float* __restrict__ whh,
    const float* __restrict__ w1, const float* __restrict__ w2,
    const float* __restrict__ p1, const float* __restrict__ p2,
    __bf16* __restrict__ WkvP, __bf16* __restrict__ WqP,
    __bf16* __restrict__ wihB, __bf16* __restrict__ whhB,
    __bf16* __restrict__ w1P, __bf16* __restrict__ w2P,
    __bf16* __restrict__ pr1P, __bf16* __restrict__ pr2P) {
  int i = blockIdx.x * 256 + threadIdx.x;
  if (i < 73728) {  // WkvP [384 cols][192 c], SCALE folded into k half
    int col = i / 192, c = i - col * 192;
    float v = (col < 192) ? Wk[c * 192 + col] * K_SCALE : Wv[c * 192 + (col - 192)];
    WkvP[i] = (__bf16)v; return;
  }
  i -= 73728;
  if (i < 36864) { int col = i / 192, c = i - col * 192; WqP[i] = (__bf16)Wq[c * 192 + col]; return; }  // [dout][e]
  i -= 36864;
  if (i < 110592) { wihB[i] = (__bf16)wih[i]; return; }       // plain [o][d]
  i -= 110592;
  if (i < 110592) { whhB[i] = (__bf16)whh[i]; return; }       // plain [o][d]
  i -= 110592;
  if (i < 147456) { int o = i / 192, c = i - o * 192; w1P[i] = (__bf16)w1[c * 768 + o]; return; }
  i -= 147456;
  if (i < 147456) { int o = i / 768, c = i - o * 768; w2P[i] = (__bf16)w2[c * 192 + o]; return; }
  i -= 147456;
  if (i < 36864) { int o = i / 192, c = i - o * 192; pr1P[i] = (__bf16)p1[c * 192 + o]; return; }
  i -= 36864;
  { int o = i / 192, c = i - o * 192; pr2P[i] = (__bf16)p2[c * 192 + o]; }
}

// ---------------- phase 1: LN(inputs) @ [Wk*SCALE | Wv] -> k (row-major), v (transposed) ----------------
__global__ __launch_bounds__(256) void p1_kernel(
    const float* __restrict__ x_in, const float* __restrict__ lng, const float* __restrict__ lnb,
    const __bf16* __restrict__ Wkv, __bf16* __restrict__ k_all, __bf16* __restrict__ v_all) {
  __shared__ __attribute__((aligned(16))) char pool[64 * 200 * 4];
  __shared__ __attribute__((aligned(16))) __bf16 xh[64 * 192];
  __shared__ float gsh[192], bsh[192];
  float* xs = (float*)pool;
  __bf16* kst = (__bf16*)pool;            // [64][192]
  __bf16* vst = (__bf16*)(pool + 24576);  // [192][64]

  const int tid = threadIdx.x;
  const int blk = blockIdx.x;
  const long Rbase = (long)blk * 64;
  if (tid < 192) { gsh[tid] = lng[tid]; bsh[tid] = lnb[tid]; }

  const float* gxp = x_in + Rbase * 192;
  for (int i = tid; i < 64 * 48; i += 256) {
    int row = i / 48, c4 = i - row * 48;
    float4 v = *(const float4*)(gxp + row * 192 + c4 * 4);
    float* d = xs + row * 200 + c4 * 4;
    d[0] = v.x; d[1] = v.y; d[2] = v.z; d[3] = v.w;
  }
  __syncthreads();

  const int r = tid >> 2, coff = (tid & 3) * 48;
  float xr[48];
  const float* src = xs + r * 200 + coff;
#pragma unroll
  for (int j = 0; j < 48; j++) xr[j] = src[j];
  float s = 0.f, sq = 0.f;
#pragma unroll
  for (int j = 0; j < 48; j++) { s += xr[j]; sq += xr[j] * xr[j]; }
  s += __shfl_xor(s, 1, 64);  s += __shfl_xor(s, 2, 64);
  sq += __shfl_xor(sq, 1, 64); sq += __shfl_xor(sq, 2, 64);
  float mu = s * (1.f / 192.f);
  float var = sq * (1.f / 192.f) - mu * mu;
  float rs = rsqrtf(var + 1e-5f);
  {
    char* xrow = (char*)xh + r * 384;
    int swz = (r & 7) << 4;
#pragma unroll
    for (int j = 0; j < 6; j++) {
      bf16x8 o;
#pragma unroll
      for (int e = 0; e < 8; e++) {
        int c = coff + j * 8 + e;
        o[e] = (__bf16)((xr[j * 8 + e] - mu) * rs * gsh[c] + bsh[c]);
      }
      *(bf16x8*)(xrow + (((coff + j * 8) * 2) ^ swz)) = o;
    }
  }
  __syncthreads();

  const int w = tid >> 6, lane = tid & 63;
  const int arow = lane & 15, kgr = lane >> 4;
  const int m0 = w * 16;
  const char* abase = (const char*)xh + m0 * 384;

#pragma unroll 1
  for (int nt = 0; nt < 12; nt++) {                  // k columns
    int col = nt * 16 + arow;
    const __bf16* bp = Wkv + col * 192 + kgr * 8;
    f32x4 acc = mmK<6>(zero4(), abase, 384, bp, lane);
#pragma unroll
    for (int rr = 0; rr < 4; rr++) kst[(m0 + kgr * 4 + rr) * 192 + col] = (__bf16)acc[rr];
  }
#pragma unroll 1
  for (int nt = 0; nt < 12; nt++) {                  // v columns, transposed staging
    int dcol = nt * 16 + arow;
    const __bf16* bp = Wkv + (192 + dcol) * 192 + kgr * 8;
    f32x4 acc = mmK<6>(zero4(), abase, 384, bp, lane);
    __bf16* vp = &vst[dcol * 64 + m0 + kgr * 4];
#pragma unroll
    for (int rr = 0; rr < 4; rr++) vp[rr] = (__bf16)acc[rr];
  }
  __syncthreads();

  {
    const uint4* s4 = (const uint4*)kst;
    uint4* d4 = (uint4*)(k_all + Rbase * 192);
    for (int i = tid; i < 1536; i += 256) d4[i] = s4[i];
  }
  {
    int bt = blk >> 2;
    int n0g = (blk & 3) * 64;
    __bf16* vout = v_all + (long)bt * 49152 + n0g;
    for (int i = tid; i < 1536; i += 256) {
      int d = i >> 3, cc = i & 7;
      *(uint4*)((char*)(vout + d * 256) + cc * 16) =
          *(const uint4*)((const char*)vst + d * 128 + cc * 16);
    }
  }
}

// ---------------- phase 2: persistent block per batch, full scan (512 threads) ----------------
__global__ __launch_bounds__(512, 1) void p2_kernel(
    const __bf16* __restrict__ k_all, const __bf16* __restrict__ v_all,
    const __bf16* __restrict__ WqP,
    const __bf16* __restrict__ wihB, const __bf16* __restrict__ whhB,
    const __bf16* __restrict__ w1P, const __bf16* __restrict__ w2P,
    const __bf16* __restrict__ pr1P, const __bf16* __restrict__ pr2P,
    const float* __restrict__ noise, const float* __restrict__ mu_p, const float* __restrict__ lsig,
    const float* __restrict__ lnsg, const float* __restrict__ lnsb,
    const float* __restrict__ lnfg, const float* __restrict__ lnfb,
    const float* __restrict__ bih, const float* __restrict__ bhh,
    const float* __restrict__ b1p, const float* __restrict__ b2p,
    const float* __restrict__ prb1, const float* __restrict__ prb2,
    float* __restrict__ out) {
  __shared__ Smem sm;
  const int tid = threadIdx.x;
  const int w = tid >> 6, lane = tid & 63;
  const int b = blockIdx.x;
  const int kgr = lane >> 4, arow = lane & 15;

  for (int i = tid; i < 192; i += 512) {
    sm.Lsg[i] = lnsg[i]; sm.Lsb[i] = lnsb[i]; sm.Lfg[i] = lnfg[i]; sm.Lfb[i] = lnfb[i];
    sm.B2s[i] = b2p[i]; sm.Pb1s[i] = prb1[i]; sm.Pb2s[i] = prb2[i];
  }
  for (int i = tid; i < 576; i += 512) { sm.Bih[i] = bih[i]; sm.Bhh[i] = bhh[i]; }
  for (int i = tid; i < 768; i += 512) sm.B1s[i] = b1p[i];
  for (int i = tid; i < 16 * 192; i += 512) {
    sm.slots_bf[i] = (__bf16)0.f; sm.ln_bf[i] = (__bf16)0.f;
    sm.q_bf[i] = (__bf16)0.f; sm.upd_bf[i] = (__bf16)0.f;
  }
  for (int i = tid; i < 16 * 256; i += 512) sm.attnT[i] = (__bf16)0.f;
  for (int i = tid; i < 16 * 768; i += 512) sm.a_bf[i] = (__bf16)0.f;
  __syncthreads();
  for (int i = tid; i < 1536; i += 512) {
    int s = i / 192, d = i - s * 192;
    float v = mu_p[d] + expf(lsig[d]) * noise[(b * 8 + s) * 192 + d];
    sm.slots[i] = v;
    st_swz(sm.slots_bf, 384, s, d, v);
  }
  __syncthreads();

  float* out_slots = out;
  float* out_dots = out + 786432;

#pragma unroll 1
  for (int t = 0; t < 16; ++t) {
    const int bt = b * 16 + t;
    const __bf16* kb = k_all + (long)bt * 49152;    // [256 n][192 d]
    const __bf16* vb = v_all + (long)bt * 49152;    // [192 d][256 n]
#pragma unroll 1
    for (int it = 0; it < 3; ++it) {
      // P1: LN(slots) — one row per wave
      {
        int s = w;
        float v0 = sm.slots[s * 192 + lane], v1 = sm.slots[s * 192 + 64 + lane], v2 = sm.slots[s * 192 + 128 + lane];
        float sum = v0 + v1 + v2, sq = v0 * v0 + v1 * v1 + v2 * v2;
#pragma unroll
        for (int m = 1; m < 64; m <<= 1) { sum += __shfl_xor(sum, m, 64); sq += __shfl_xor(sq, m, 64); }
        float mu = sum * (1.f / 192.f);
        float var = sq * (1.f / 192.f) - mu * mu;
        float rs = rsqrtf(var + 1e-5f);
        st_swz(sm.ln_bf, 384, s, lane,       (v0 - mu) * rs * sm.Lsg[lane]       + sm.Lsb[lane]);
        st_swz(sm.ln_bf, 384, s, lane + 64,  (v1 - mu) * rs * sm.Lsg[lane + 64]  + sm.Lsb[lane + 64]);
        st_swz(sm.ln_bf, 384, s, lane + 128, (v2 - mu) * rs * sm.Lsg[lane + 128] + sm.Lsb[lane + 128]);
      }
      __syncthreads();
      // P2: q = ln @ Wq (12 jobs) + gh jobs 0..3
#pragma unroll 1
      for (int jx = w; jx < 16; jx += 8) {
        if (jx < 12) {
          const __bf16* bp = WqP + (jx * 16 + arow) * 192 + kgr * 8;
          f32x4 acc = mmK<6>(zero4(), (const char*)sm.ln_bf, 384, bp, lane);
          st_q_swz(sm.q_bf, acc, jx * 16, lane);
        } else {
          int j2 = jx - 12;  // 0..3
          const __bf16* bp = whhB + (j2 * 16 + arow) * 192 + kgr * 8;
          f32x4 acc = mmK<6>(zero4(), (const char*)sm.slots_bf, 384, bp, lane);
          st_f32(sm.gh, acc, j2 * 16, lane);
        }
      }
      __syncthreads();
      // P3: dots^T = q @ k^T, softmax over s, attnT (+eps, bf16), part_cs — 16 jobs
#pragma unroll 1
      for (int j = w; j < 16; j += 8) {
        const __bf16* bp = kb + (j * 16 + arow) * 192 + kgr * 8;
        f32x4 acc = mmK<6>(zero4(), (const char*)sm.q_bf, 384, bp, lane);
        float m4 = fmaxf(fmaxf(acc[0], acc[1]), fmaxf(acc[2], acc[3]));
        float m8 = fmaxf(m4, __shfl_xor(m4, 16, 64));
        float e0 = __expf(acc[0] - m8), e1 = __expf(acc[1] - m8);
        float e2 = __expf(acc[2] - m8), e3 = __expf(acc[3] - m8);
        float s4 = e0 + e1 + e2 + e3;
        float den = s4 + __shfl_xor(s4, 16, 64);
        float rden = 1.f / den;
        if (kgr < 2) {
          int n = j * 16 + arow;
          float a0 = e0 * rden, a1 = e1 * rden, a2 = e2 * rden, a3 = e3 * rden;
          if (it == 2)
            *(float4*)(out_dots + ((long)bt * 256 + n) * 8 + kgr * 4) = make_float4(a0, a1, a2, a3);
          __bf16 q0 = (__bf16)(a0 + ATTN_EPS), q1 = (__bf16)(a1 + ATTN_EPS);
          __bf16 q2 = (__bf16)(a2 + ATTN_EPS), q3 = (__bf16)(a3 + ATTN_EPS);
          int r0 = kgr * 4;
          char* base = (char*)sm.attnT;
          *(__bf16*)(base + (r0 + 0) * 512 + ((n * 2) ^ (((r0 + 0) & 7) << 4))) = q0;
          *(__bf16*)(base + (r0 + 1) * 512 + ((n * 2) ^ (((r0 + 1) & 7) << 4))) = q1;
          *(__bf16*)(base + (r0 + 2) * 512 + ((n * 2) ^ (((r0 + 2) & 7) << 4))) = q2;
          *(__bf16*)(base + (r0 + 3) * 512 + ((n * 2) ^ (((r0 + 3) & 7) << 4))) = q3;
          float c0 = (float)q0, c1 = (float)q1, c2 = (float)q2, c3 = (float)q3;
#pragma unroll
          for (int m = 1; m < 16; m <<= 1) {
            c0 += __shfl_xor(c0, m, 64); c1 += __shfl_xor(c1, m, 64);
            c2 += __shfl_xor(c2, m, 64); c3 += __shfl_xor(c3, m, 64);
          }
          if (arow == 0) {
            sm.part_cs[j * 8 + r0 + 0] = c0; sm.part_cs[j * 8 + r0 + 1] = c1;
            sm.part_cs[j * 8 + r0 + 2] = c2; sm.part_cs[j * 8 + r0 + 3] = c3;
          }
        }
      }
      __syncthreads();
      // P4: upd = attnT@v^T / colsum (12 jobs) + gh jobs 4..31
      {
        float cs[4];
#pragma unroll
        for (int rr = 0; rr < 4; rr++) {
          float s = 0.f;
#pragma unroll 1
          for (int jj = 0; jj < 16; jj++) s += sm.part_cs[jj * 8 + ((kgr * 4 + rr) & 7)];
          cs[rr] = s;
        }
#pragma unroll 1
        for (int jx = w; jx < 40; jx += 8) {
          if (jx < 12) {
            const __bf16* bp = vb + (jx * 16 + arow) * 256 + kgr * 8;
            f32x4 acc = mmK<8>(zero4(), (const char*)sm.attnT, 512, bp, lane);
            if (kgr < 2) {
              int col = jx * 16 + arow;
#pragma unroll
              for (int rr = 0; rr < 4; rr++)
                st_swz(sm.upd_bf, 384, kgr * 4 + rr, col, acc[rr] / cs[rr]);
            }
          } else {
            int j2 = jx - 8;  // 4..31
            const __bf16* bp = whhB + (j2 * 16 + arow) * 192 + kgr * 8;
            f32x4 acc = mmK<6>(zero4(), (const char*)sm.slots_bf, 384, bp, lane);
            st_f32(sm.gh, acc, j2 * 16, lane);
          }
        }
      }
      __syncthreads();
      // P5: gx = upd@wih^T (36 jobs) + gh jobs 32..35
#pragma unroll 1
      for (int jx = w; jx < 40; jx += 8) {
        if (jx < 36) {
          const __bf16* bp = wihB + (jx * 16 + arow) * 192 + kgr * 8;
          f32x4 acc = mmK<6>(zero4(), (const char*)sm.upd_bf, 384, bp, lane);
          st_f32(sm.gx, acc, jx * 16, lane);
        } else {
          int j2 = jx - 4;  // 32..35
          const __bf16* bp = whhB + (j2 * 16 + arow) * 192 + kgr * 8;
          f32x4 acc = mmK<6>(zero4(), (const char*)sm.slots_bf, 384, bp, lane);
          st_f32(sm.gh, acc, j2 * 16, lane);
        }
      }
      __syncthreads();
      // P6: GRU gates (exact math) + fused FF-LayerNorm
      {
        int s = w;
        float nh[3];
#pragma unroll
        for (int j = 0; j < 3; j++) {
          int d = lane + j * 64;
          float xr = sm.gx[s * 577 + d]       + sm.Bih[d];
          float xz = sm.gx[s * 577 + 192 + d] + sm.Bih[192 + d];
          float xn = sm.gx[s * 577 + 384 + d] + sm.Bih[384 + d];
          float hr = sm.gh[s * 577 + d]       + sm.Bhh[d];
          float hz = sm.gh[s * 577 + 192 + d] + sm.Bhh[192 + d];
          float hn = sm.gh[s * 577 + 384 + d] + sm.Bhh[384 + d];
          float rg = 1.f / (1.f + __expf(-(xr + hr)));
          float zg = 1.f / (1.f + __expf(-(xz + hz)));
          float ng = tanhf(xn + rg * hn);
          float hv = sm.slots[s * 192 + d];
          float v = (1.f - zg) * ng + zg * hv;
          nh[j] = v;
          sm.slots[s * 192 + d] = v;
          st_swz(sm.slots_bf, 384, s, d, v);
        }
        if (it < 2) {
          float sum = nh[0] + nh[1] + nh[2], sq = nh[0] * nh[0] + nh[1] * nh[1] + nh[2] * nh[2];
#pragma unroll
          for (int m = 1; m < 64; m <<= 1) { sum += __shfl_xor(sum, m, 64); sq += __shfl_xor(sq, m, 64); }
          float mu = sum * (1.f / 192.f);
          float var = sq * (1.f / 192.f) - mu * mu;
          float rs = rsqrtf(var + 1e-5f);
#pragma unroll
          for (int j = 0; j < 3; j++) {
            int d = lane + j * 64;
            st_swz(sm.ln_bf, 384, s, d, (nh[j] - mu) * rs * sm.Lfg[d] + sm.Lfb[d]);
          }
        }
      }
      __syncthreads();
      if (it < 2) {
        // P7: MLP1 — 48 jobs
#pragma unroll 1
        for (int j = w; j < 48; j += 8) {
          const __bf16* bp = w1P + (j * 16 + arow) * 192 + kgr * 8;
          f32x4 acc = mmK<6>(zero4(), (const char*)sm.ln_bf, 384, bp, lane);
          st_relu_swz(sm.a_bf, 1536, acc, j * 16, sm.B1s, lane);
        }
        __syncthreads();
        // P8: MLP2 + residual — 12 jobs (K=768 in 4 chunks)
#pragma unroll 1
        for (int j = w; j < 12; j += 8) {
          f32x4 acc = zero4();
#pragma unroll 1
          for (int c = 0; c < 4; c++) {
            const __bf16* bp = w2P + (j * 16 + arow) * 768 + c * 192 + kgr * 8;
            acc = mmK<6>(acc, (const char*)sm.a_bf + c * 384, 1536, bp, lane);
          }
          if (kgr < 2) {
            int col = j * 16 + arow;
#pragma unroll
            for (int rr = 0; rr < 4; rr++) {
              int s = kgr * 4 + rr;
              float nv = sm.slots[s * 192 + col] + acc[rr] + sm.B2s[col];
              sm.slots[s * 192 + col] = nv;
              st_swz(sm.slots_bf, 384, s, col, nv);
            }
          }
        }
        __syncthreads();
      }
    }  // it
    // PA: prior MLP layer 1 (12 jobs) + out_slots store
#pragma unroll 1
    for (int j = w; j < 12; j += 8) {
      const __bf16* bp = pr1P + (j * 16 + arow) * 192 + kgr * 8;
      f32x4 acc = mmK<6>(zero4(), (const char*)sm.slots_bf, 384, bp, lane);
      st_relu_swz(sm.ln_bf, 384, acc, j * 16, sm.Pb1s, lane);
    }
    for (int i = tid; i < 384; i += 512)
      *(float4*)(out_slots + (long)bt * 1536 + i * 4) = *(const float4*)(&sm.slots[i * 4]);
    __syncthreads();
    // PB: prior MLP layer 2 -> carried slots
#pragma unroll 1
    for (int j = w; j < 12; j += 8) {
      const __bf16* bp = pr2P + (j * 16 + arow) * 192 + kgr * 8;
      f32x4 acc = mmK<6>(zero4(), (const char*)sm.ln_bf, 384, bp, lane);
      if (kgr < 2) {
        int col = j * 16 + arow;
#pragma unroll
        for (int rr = 0; rr < 4; rr++) {
          int s = kgr * 4 + rr;
          float nv = acc[rr] + sm.Pb2s[col];
          sm.slots[s * 192 + col] = nv;
          st_swz(sm.slots_bf, 384, s, col, nv);
        }
      }
    }
    __syncthreads();
  }  // t
}

extern "C" void kernel_launch(void* const* d_in, const int* in_sizes, int n_in,
                              void* d_out, int out_size, void* d_ws, size_t ws_size,
                              hipStream_t stream) {
  const float* inputs = (const float*)d_in[0];
  const float* noise  = (const float*)d_in[1];
  const float* mu     = (const float*)d_in[2];
  const float* lsig   = (const float*)d_in[3];
  const float* ln_in_g = (const float*)d_in[4];
  const float* ln_in_b = (const float*)d_in[5];
  const float* Wk = (const float*)d_in[6];
  const float* Wv = (const float*)d_in[7];
  const float* Wq = (const float*)d_in[8];
  const float* lnsg = (const float*)d_in[9];
  const float* lnsb = (const float*)d_in[10];
  const float* wih = (const float*)d_in[11];
  const float* whh = (const float*)d_in[12];
  const float* bih = (const float*)d_in[13];
  const float* bhh = (const float*)d_in[14];
  const float* lnfg = (const float*)d_in[15];
  const float* lnfb = (const float*)d_in[16];
  const float* w1 = (const float*)d_in[17];
  const float* b1 = (const float*)d_in[18];
  const float* w2 = (const float*)d_in[19];
  const float* b2 = (const float*)d_in[20];
  const float* pw1 = (const float*)d_in[21];
  const float* pb1 = (const float*)d_in[22];
  const float* pw2 = (const float*)d_in[23];
  const float* pb2 = (const float*)d_in[24];

  char* ws = (char*)d_ws;
  __bf16* WkvP = (__bf16*)(ws + 0);
  __bf16* WqP  = (__bf16*)(ws + 147456);
  __bf16* wihB = (__bf16*)(ws + 221184);
  __bf16* whhB = (__bf16*)(ws + 442368);
  __bf16* w1P  = (__bf16*)(ws + 663552);
  __bf16* w2P  = (__bf16*)(ws + 958464);
  __bf16* pr1P = (__bf16*)(ws + 1253376);
  __bf16* pr2P = (__bf16*)(ws + 1327104);
  __bf16* k_all = (__bf16*)(ws + 1400832);   // k row-major per bt
  __bf16* v_all = (__bf16*)(ws + 51732480);  // v transposed per bt
  // total ws usage: 102064128 bytes

  prep_kernel<<<2736, 256, 0, stream>>>(Wk, Wv, Wq, wih, whh, w1, w2, pw1, pw2,
                                        WkvP, WqP, wihB, whhB, w1P, w2P, pr1P, pr2P);
  p1_kernel<<<2048, 256, 0, stream>>>(inputs, ln_in_g, ln_in_b, WkvP, k_all, v_all);
  p2_kernel<<<32, 512, 0, stream>>>(k_all, v_all, WqP, wihB, whhB, w1P, w2P, pr1P, pr2P,
                                    noise, mu, lsig, lnsg, lnsb, lnfg, lnfb,
                                    bih, bhh, b1, b2, pb1, pb2, (float*)d_out);
}